// Round 6
// baseline (101.006 us; speedup 1.0000x reference)
//
#include <hip/hip_runtime.h>
#include <hip/hip_bf16.h>

#define HWSZ 12544   // 112*112
#define WDIM 112
#define CIN  128
#define NPIX 25088   // B*HWSZ, B=2

typedef __attribute__((ext_vector_type(8))) short          short8;
typedef __attribute__((ext_vector_type(4))) float          float4v;
typedef __attribute__((ext_vector_type(4))) unsigned short ushort4v;

// NATTEN window start for K=7, D=2
__device__ __forceinline__ int window_start7x2(int idx, int L) {
    int ni = idx - 6;
    int imodd = idx & 1;
    int a = (L >> 1) << 1;
    int bb = L - a;
    int right = (imodd < bb) ? (L - bb + imodd - 12) : (a + imodd - 14);
    if (ni < 0) return imodd;
    if (idx + 6 >= L) return right;
    return ni;
}

__device__ __forceinline__ unsigned short f2bf(float f) {
    __hip_bfloat16 h = __float2bfloat16(f);
    return *(unsigned short*)&h;
}
__device__ __forceinline__ float bf2f(unsigned short u) {
    __hip_bfloat16 h = *(__hip_bfloat16*)&u;
    return __bfloat162float(h);
}

// ---------------------------------------------------------------------------
// Projection: ONE block does q,k,v for its 64-pixel tile (x gathered once).
// All three W staged in LDS bf16 (52 KB). grid 392 x 256 thr.
// q pre-scaled by 0.125 (fold 64^-0.5).
// ---------------------------------------------------------------------------
__global__ __launch_bounds__(256) void proj_mfma(
    const float* __restrict__ x,
    const float* __restrict__ Wq, const float* __restrict__ bq,
    const float* __restrict__ Wk, const float* __restrict__ bk,
    const float* __restrict__ Wv, const float* __restrict__ bv,
    unsigned short* __restrict__ qkv)
{
    __shared__ __align__(16) unsigned short wsb[3][64][136];  // [m][out][c], pad 8

    const int t = threadIdx.x, lane = t & 63, wv = t >> 6, quad = lane >> 4;

    const int pix0 = blockIdx.x * 64;           // HWSZ % 64 == 0: no b-straddle
    const int b    = pix0 / HWSZ;
    const int hw0  = pix0 - b * HWSZ;
    const float* xb = x + (size_t)b * CIN * HWSZ;

    // stage all 3 W (fp32 -> bf16): 24576 floats = 6144 float4, 24 per thread
    const float* Ws[3] = {Wq, Wk, Wv};
    #pragma unroll
    for (int i = 0; i < 24; ++i) {
        int u   = i * 256 + t;
        int m   = u >> 11;
        int rem = u & 2047;
        int o = rem >> 5, cq = (rem & 31) * 4;
        float4 w4 = *(const float4*)&Ws[m][o * 128 + cq];
        ushort4v s4 = { f2bf(w4.x), f2bf(w4.y), f2bf(w4.z), f2bf(w4.w) };
        *(ushort4v*)&wsb[m][o][cq] = s4;
    }

    // A-fragments direct from global (once, reused for all 3 m):
    // px = wv*16 + (lane&15), ch = kc*32 + quad*8 + j
    const int hwpx = hw0 + wv * 16 + (lane & 15);
    short8 af[4];
    #pragma unroll
    for (int kc = 0; kc < 4; ++kc) {
        #pragma unroll
        for (int j = 0; j < 8; ++j) {
            int c = kc * 32 + quad * 8 + j;
            af[kc][j] = (short)f2bf(xb[(size_t)c * HWSZ + hwpx]);
        }
    }
    __syncthreads();

    const float* bs[3] = {bq, bk, bv};
    #pragma unroll
    for (int m = 0; m < 3; ++m) {
        float4v acc[4] = {{0,0,0,0},{0,0,0,0},{0,0,0,0},{0,0,0,0}};
        #pragma unroll
        for (int kc = 0; kc < 4; ++kc) {
            #pragma unroll
            for (int nt = 0; nt < 4; ++nt) {
                short8 bf = *(const short8*)&wsb[m][nt * 16 + (lane & 15)][kc * 32 + quad * 8];
                acc[nt] = __builtin_amdgcn_mfma_f32_16x16x32_bf16(af[kc], bf, acc[nt], 0, 0, 0);
            }
        }
        const float scale = (m == 0) ? 0.125f : 1.0f;
        unsigned short* outm = qkv + (size_t)m * NPIX * 64;
        #pragma unroll
        for (int nt = 0; nt < 4; ++nt) {
            int o = nt * 16 + (lane & 15);
            float bias = bs[m][o];
            #pragma unroll
            for (int r = 0; r < 4; ++r) {
                int px = wv * 16 + quad * 4 + r;        // D: row = quad*4 + reg
                outm[(size_t)(pix0 + px) * 64 + o] = f2bf((acc[nt][r] + bias) * scale);
            }
        }
    }
}

// ---------------------------------------------------------------------------
// Attention: tile = 16 same-parity pixels of one row; key union 7x22=154
// (padded 160). Q/K/V fragments ALL direct from global (L1/L2-hot);
// LDS = ps (score/P matrix) only, 5.4 KB. grid 1792 x 256 thr.
// ---------------------------------------------------------------------------
__global__ __launch_bounds__(256) void attn_mfma(
    const unsigned short* __restrict__ qkv, float* __restrict__ out)
{
    __shared__ __align__(16) unsigned short ps[16 * 168];   // [px][key], bf16

    const int t = threadIdx.x, lane = t & 63, wv = t >> 6, quad = lane >> 4;
    const int bx  = blockIdx.x;
    const int b   = bx / 896;  const int rem = bx - b * 896;
    const int h   = rem >> 3;  const int sub = rem & 7;
    const int g   = sub & 1;
    const int pbi = sub >> 1;
    const int pb  = (pbi < 3) ? pbi * 16 : 40;   // last tile overlaps (benign)

    const int hs  = window_start7x2(h, WDIM);
    const int ws0 = window_start7x2(2 * pb + g, WDIM);
    const int pixbase = b * HWSZ;

    const unsigned short* qg = qkv;
    const unsigned short* kg = qkv + (size_t)NPIX * 64;
    const unsigned short* vg = qkv + 2 * (size_t)NPIX * 64;

    // ---- Q A-fragments direct from global
    const int qpix = pixbase + h * WDIM + 2 * (pb + (lane & 15)) + g;
    short8 af[2];
    #pragma unroll
    for (int kc = 0; kc < 2; ++kc)
        af[kc] = *(const short8*)(qg + (size_t)qpix * 64 + kc * 32 + quad * 8);

    // per-lane window bases for its 4 D-rows (px = quad*4 + r)
    int cb_r[4];
    #pragma unroll
    for (int r = 0; r < 4; ++r) {
        int px = quad * 4 + r;
        cb_r[r] = (window_start7x2(2 * (pb + px) + g, WDIM) - ws0) >> 1;
    }

    // ---- scores: S[16][160] = Q(16x64) * K^T; K B-fragments direct global
    for (int nt = wv; nt < 10; nt += 4) {
        int keyb = nt * 16 + (lane & 15);
        int i = (unsigned)keyb / 22u, c = keyb - i * 22;
        int kw = ws0 + 2 * c; if (kw > 111) kw = 111;
        int kp = pixbase + (hs + 2 * i) * WDIM + kw;
        if (keyb >= 154) kp = pixbase;          // keep address in-bounds
        float4v acc = {0,0,0,0};
        #pragma unroll
        for (int kc = 0; kc < 2; ++kc) {
            short8 bf = *(const short8*)(kg + (size_t)kp * 64 + kc * 32 + quad * 8);
            acc = __builtin_amdgcn_mfma_f32_16x16x32_bf16(af[kc], bf, acc, 0, 0, 0);
        }
        bool colok = (keyb < 154);
        #pragma unroll
        for (int r = 0; r < 4; ++r) {
            bool valid = colok && ((unsigned)(c - cb_r[r]) < 7u);
            float sv = valid ? acc[r] : -1e30f;
            int px = quad * 4 + r;
            ps[px * 168 + keyb] = f2bf(sv);
        }
    }
    __syncthreads();

    // ---- softmax: 16 threads per px-row
    {
        const int row = t >> 4, slot = t & 15;
        float sv[10]; float mx = -1e30f;
        #pragma unroll
        for (int k2 = 0; k2 < 10; ++k2) {
            sv[k2] = bf2f(ps[row * 168 + slot + 16 * k2]);
            mx = fmaxf(mx, sv[k2]);
        }
        #pragma unroll
        for (int msk = 1; msk < 16; msk <<= 1)
            mx = fmaxf(mx, __shfl_xor(mx, msk, 64));
        float sum = 0.0f;
        #pragma unroll
        for (int k2 = 0; k2 < 10; ++k2) {
            sv[k2] = __expf(sv[k2] - mx);       // masked -> exp(-huge) = 0
            sum += sv[k2];
        }
        #pragma unroll
        for (int msk = 1; msk < 16; msk <<= 1)
            sum += __shfl_xor(sum, msk, 64);
        float rinv = 1.0f / sum;
        #pragma unroll
        for (int k2 = 0; k2 < 10; ++k2)
            ps[row * 168 + slot + 16 * k2] = f2bf(sv[k2] * rinv);
    }
    __syncthreads();

    // ---- PV: O[16][64] = P(16x160) * V(160x64); wave wv owns ch-tile wv.
    // V B-fragments direct from global: lane needs V[key = kc*32+quad*8+j][ch].
    // Invalid keys have P == 0; fetched values only need to be finite.
    const int ch = wv * 16 + (lane & 15);
    float4v oacc = {0,0,0,0};
    #pragma unroll
    for (int kc = 0; kc < 5; ++kc) {
        short8 pa = *(const short8*)&ps[(lane & 15) * 168 + kc * 32 + quad * 8];
        short8 vb;
        #pragma unroll
        for (int j = 0; j < 8; ++j) {
            int key = kc * 32 + quad * 8 + j;
            int i = (unsigned)key / 22u, c = key - i * 22;
            int kw = ws0 + 2 * c; if (kw > 111) kw = 111;
            int kp = (key < 154) ? (pixbase + (hs + 2 * i) * WDIM + kw) : pixbase;
            vb[j] = (short)vg[(size_t)kp * 64 + ch];
        }
        oacc = __builtin_amdgcn_mfma_f32_16x16x32_bf16(pa, vb, oacc, 0, 0, 0);
    }
    {
        float* ob = out + (size_t)(b * 64 + ch) * HWSZ + h * WDIM;
        #pragma unroll
        for (int r = 0; r < 4; ++r) {
            int px = quad * 4 + r;
            ob[2 * (pb + px) + g] = oacc[r];
        }
    }
}

// ---------------------------------------------------------------------------
extern "C" void kernel_launch(void* const* d_in, const int* in_sizes, int n_in,
                              void* d_out, int out_size, void* d_ws, size_t ws_size,
                              hipStream_t stream) {
    const float* x  = (const float*)d_in[0];
    const float* Wq = (const float*)d_in[1];
    const float* bq = (const float*)d_in[2];
    const float* Wk = (const float*)d_in[3];
    const float* bk = (const float*)d_in[4];
    const float* Wv = (const float*)d_in[5];
    const float* bv = (const float*)d_in[6];
    float* out = (float*)d_out;

    unsigned short* qkv = (unsigned short*)d_ws;  // [3][NPIX][64] bf16 = 9.6 MB

    proj_mfma<<<dim3(392), dim3(256), 0, stream>>>(x, Wq, bq, Wk, bk, Wv, bv, qkv);
    attn_mfma<<<dim3(1792), dim3(256), 0, stream>>>(qkv, out);
}

// Round 7
// 99.897 us; speedup vs baseline: 1.0111x; 1.0111x over previous
//
#include <hip/hip_runtime.h>
#include <hip/hip_bf16.h>

#define HWSZ 12544   // 112*112
#define WDIM 112
#define CIN  128
#define NPIX 25088   // B*HWSZ, B=2
#define VTROW 6272   // 112*56, one (b,g,ch) plane of vt

typedef __attribute__((ext_vector_type(8))) short          short8;
typedef __attribute__((ext_vector_type(4))) float          float4v;
typedef __attribute__((ext_vector_type(4))) unsigned short ushort4v;

// NATTEN window start for K=7, D=2
__device__ __forceinline__ int window_start7x2(int idx, int L) {
    int ni = idx - 6;
    int imodd = idx & 1;
    int a = (L >> 1) << 1;
    int bb = L - a;
    int right = (imodd < bb) ? (L - bb + imodd - 12) : (a + imodd - 14);
    if (ni < 0) return imodd;
    if (idx + 6 >= L) return right;
    return ni;
}

__device__ __forceinline__ unsigned short f2bf(float f) {
    __hip_bfloat16 h = __float2bfloat16(f);
    return *(unsigned short*)&h;
}

// ---------------------------------------------------------------------------
// Projection GEMM via MFMA (round-5 structure). A-fragments direct from x;
// W staged in LDS. grid (392, 3) x 256 thr. m==0: q (pre-scaled 0.125), m==1: k
// (both natural [pix][64]); m==2: v written parity-split transposed:
//   vt[((b*2 + (w&1))*64 + ch)][h][w>>1]
// ---------------------------------------------------------------------------
__global__ __launch_bounds__(256) void proj_mfma(
    const float* __restrict__ x,
    const float* __restrict__ Wq, const float* __restrict__ bq,
    const float* __restrict__ Wk, const float* __restrict__ bk,
    const float* __restrict__ Wv, const float* __restrict__ bv,
    unsigned short* __restrict__ qbuf)
{
    __shared__ __align__(16) unsigned short wsb[64][136];  // [out][c], pad 8

    const int t = threadIdx.x, lane = t & 63, wv = t >> 6, quad = lane >> 4;
    const int m = blockIdx.y;
    const float* Wm = (m == 0) ? Wq : (m == 1) ? Wk : Wv;
    const float* bm = (m == 0) ? bq : (m == 1) ? bk : bv;

    const int pix0 = blockIdx.x * 64;           // HWSZ % 64 == 0: no b-straddle
    const int b    = blockIdx.x / 196;
    const int hw0  = pix0 - b * HWSZ;
    const float* xb = x + (size_t)b * CIN * HWSZ;

    // stage W tile [out][c] (fp32 -> bf16)
    #pragma unroll
    for (int i = 0; i < 8; ++i) {
        int u = t + 256 * i;
        int o = u >> 5, cq = (u & 31) * 4;
        float4 w4 = *(const float4*)&Wm[o * 128 + cq];
        ushort4v s4 = { f2bf(w4.x), f2bf(w4.y), f2bf(w4.z), f2bf(w4.w) };
        *(ushort4v*)&wsb[o][cq] = s4;
    }

    // A-fragments direct from global: px = wv*16+(lane&15), ch = kc*32+quad*8+j
    const int hwpx = hw0 + wv * 16 + (lane & 15);
    short8 af[4];
    #pragma unroll
    for (int kc = 0; kc < 4; ++kc) {
        #pragma unroll
        for (int j = 0; j < 8; ++j) {
            int c = kc * 32 + quad * 8 + j;
            af[kc][j] = (short)f2bf(xb[(size_t)c * HWSZ + hwpx]);
        }
    }
    __syncthreads();

    float4v acc[4] = {{0,0,0,0},{0,0,0,0},{0,0,0,0},{0,0,0,0}};
    #pragma unroll
    for (int kc = 0; kc < 4; ++kc) {
        #pragma unroll
        for (int nt = 0; nt < 4; ++nt) {
            short8 bf = *(const short8*)&wsb[nt * 16 + (lane & 15)][kc * 32 + quad * 8];
            acc[nt] = __builtin_amdgcn_mfma_f32_16x16x32_bf16(af[kc], bf, acc[nt], 0, 0, 0);
        }
    }

    if (m < 2) {
        const float scale = (m == 0) ? 0.125f : 1.0f;
        unsigned short* outm = qbuf + (size_t)m * NPIX * 64;
        #pragma unroll
        for (int nt = 0; nt < 4; ++nt) {
            int o = nt * 16 + (lane & 15);
            float bias = bm[o];
            #pragma unroll
            for (int r = 0; r < 4; ++r) {
                int px = wv * 16 + quad * 4 + r;    // D: row = quad*4 + reg
                outm[(size_t)(pix0 + px) * 64 + o] = f2bf(acc[nt][r] + bias);
            }
        }
    } else {
        unsigned short* vt = qbuf + 2 * (size_t)NPIX * 64;
        #pragma unroll
        for (int nt = 0; nt < 4; ++nt) {
            int ch = nt * 16 + (lane & 15);
            float bias = bm[ch];
            #pragma unroll
            for (int r = 0; r < 4; ++r) {
                int hw = hw0 + wv * 16 + quad * 4 + r;
                int h2 = (unsigned)hw / 112u;
                int w  = hw - h2 * 112;
                vt[(size_t)((b * 2 + (w & 1)) * 64 + ch) * VTROW + h2 * 56 + (w >> 1)]
                    = f2bf(acc[nt][r] + bias);
            }
        }
    }
}

// ---------------------------------------------------------------------------
// Attention: ONE WAVE per 16-px tile, 64-thread blocks, no barriers.
// Key space u = i*32 + c (7 rows x 32 padded cols, cols relative to cb0 =
// (window_start>>1) & ~7 so all fragments are 16B-aligned). K=224 -> 14 score
// n-tiles, 7 PV kc-tiles. S in registers; softmax in-register; P transits a
// wave-private LDS buffer for the D->A layout transform. PV B-frags are single
// b128 loads from vt. grid 1792 = 2(b)*112(h)*2(parity)*4(px-group) x 64 thr.
// ---------------------------------------------------------------------------
__global__ __launch_bounds__(64) void attn_mfma(
    const unsigned short* __restrict__ qkv, float* __restrict__ out)
{
    __shared__ __align__(16) unsigned short ps[16 * 232];   // [px][u], pitch 232

    const int lane = threadIdx.x, quad = lane >> 4, col = lane & 15;
    const int bx  = blockIdx.x;
    const int b   = bx / 896;  const int rem = bx - b * 896;
    const int h   = rem >> 3;  const int sub = rem & 7;
    const int g   = sub & 1;
    const int pbi = sub >> 1;
    const int pb  = (pbi < 3) ? pbi * 16 : 40;   // last tile overlaps (benign)

    const int hs  = window_start7x2(h, WDIM);
    const int ws0 = window_start7x2(2 * pb + g, WDIM);
    const int cb0 = (ws0 >> 1) & ~7;             // 8-aligned col base
    const int pixbase = b * HWSZ;

    const unsigned short* qg = qkv;
    const unsigned short* kg = qkv + (size_t)NPIX * 64;
    const unsigned short* vt = qkv + 2 * (size_t)NPIX * 64
                             + (size_t)(b * 2 + g) * 64 * VTROW;

    // ---- Q A-fragments (m = col = px, k = ch)
    const int qpix = pixbase + h * WDIM + 2 * (pb + col) + g;
    short8 af0 = *(const short8*)(qg + (size_t)qpix * 64 + quad * 8);
    short8 af1 = *(const short8*)(qg + (size_t)qpix * 64 + 32 + quad * 8);

    // per-lane window col bases (relative to cb0) for rows px = quad*4 + r
    int cbr[4];
    #pragma unroll
    for (int r = 0; r < 4; ++r)
        cbr[r] = (window_start7x2(2 * (pb + quad * 4 + r) + g, WDIM) >> 1) - cb0;

    // ---- scores: S[16][224], 14 n-tiles x 2 MFMA (K-dim = 64 ch)
    float4v S[14];
    #pragma unroll
    for (int nt = 0; nt < 14; ++nt) {
        int u = nt * 16 + col;
        int i = u >> 5, c = u & 31;
        int wcol = cb0 + c;
        int kw = 2 * wcol + g; kw = (kw > 111) ? 111 : kw;   // addr guard
        int kp = pixbase + (hs + 2 * i) * WDIM + kw;
        float4v a = {0, 0, 0, 0};
        a = __builtin_amdgcn_mfma_f32_16x16x32_bf16(
                af0, *(const short8*)(kg + (size_t)kp * 64 + quad * 8), a, 0, 0, 0);
        a = __builtin_amdgcn_mfma_f32_16x16x32_bf16(
                af1, *(const short8*)(kg + (size_t)kp * 64 + 32 + quad * 8), a, 0, 0, 0);
        bool colok = (wcol <= 55);
        #pragma unroll
        for (int r = 0; r < 4; ++r) {
            bool valid = colok && ((unsigned)(c - cbr[r]) < 7u);
            S[nt][r] = valid ? a[r] * 0.125f : -1e30f;   // scale = 64^-0.5
        }
    }

    // ---- softmax per row (row = quad*4 + r; cols spread over 16 lanes x 14 nt)
    #pragma unroll
    for (int r = 0; r < 4; ++r) {
        float mx = S[0][r];
        #pragma unroll
        for (int nt = 1; nt < 14; ++nt) mx = fmaxf(mx, S[nt][r]);
        #pragma unroll
        for (int msk = 1; msk < 16; msk <<= 1)
            mx = fmaxf(mx, __shfl_xor(mx, msk, 64));
        float sum = 0.0f;
        #pragma unroll
        for (int nt = 0; nt < 14; ++nt) {
            float e = __expf(S[nt][r] - mx);    // masked -> 0
            S[nt][r] = e;
            sum += e;
        }
        #pragma unroll
        for (int msk = 1; msk < 16; msk <<= 1)
            sum += __shfl_xor(sum, msk, 64);
        float rinv = 1.0f / sum;
        int row = quad * 4 + r;
        #pragma unroll
        for (int nt = 0; nt < 14; ++nt)
            ps[row * 232 + nt * 16 + col] = f2bf(S[nt][r] * rinv);
    }
    // no barrier needed: single wave, lgkmcnt orders ds_write -> ds_read

    // ---- PV: O[16][64] = P(16x224) * V(224x64); B-frag = one b128 from vt
    float4v O[4] = {{0,0,0,0},{0,0,0,0},{0,0,0,0},{0,0,0,0}};
    #pragma unroll
    for (int kc = 0; kc < 7; ++kc) {
        short8 pa = *(const short8*)&ps[col * 232 + kc * 32 + quad * 8];
        int u8 = kc * 32 + quad * 8;
        int i = u8 >> 5, c0 = u8 & 31;
        int rowoff = (hs + 2 * i) * 56 + cb0 + c0;   // 8-u16 (16B) aligned
        #pragma unroll
        for (int nt = 0; nt < 4; ++nt) {
            short8 vb = *(const short8*)(vt + (size_t)(nt * 16 + col) * VTROW + rowoff);
            O[nt] = __builtin_amdgcn_mfma_f32_16x16x32_bf16(pa, vb, O[nt], 0, 0, 0);
        }
    }

    // ---- store (B, C, H, W); D: row px = quad*4+r, col ch = nt*16+col
    #pragma unroll
    for (int nt = 0; nt < 4; ++nt) {
        int ch = nt * 16 + col;
        float* ob = out + (size_t)(b * 64 + ch) * HWSZ + h * WDIM;
        #pragma unroll
        for (int r = 0; r < 4; ++r)
            ob[2 * (pb + quad * 4 + r) + g] = O[nt][r];
    }
}

// ---------------------------------------------------------------------------
extern "C" void kernel_launch(void* const* d_in, const int* in_sizes, int n_in,
                              void* d_out, int out_size, void* d_ws, size_t ws_size,
                              hipStream_t stream) {
    const float* x  = (const float*)d_in[0];
    const float* Wq = (const float*)d_in[1];
    const float* bq = (const float*)d_in[2];
    const float* Wk = (const float*)d_in[3];
    const float* bk = (const float*)d_in[4];
    const float* Wv = (const float*)d_in[5];
    const float* bv = (const float*)d_in[6];
    float* out = (float*)d_out;

    // d_ws layout: q [NPIX][64] u16 | k [NPIX][64] u16 | vt [256][6272] u16 (+slack)
    unsigned short* qkv = (unsigned short*)d_ws;   // ~9.6 MB + slack << ws_size

    proj_mfma<<<dim3(392, 3), dim3(256), 0, stream>>>(x, Wq, bq, Wk, bk, Wv, bv, qkv);
    attn_mfma<<<dim3(1792), dim3(64), 0, stream>>>(qkv, out);
}

// Round 8
// 98.360 us; speedup vs baseline: 1.0269x; 1.0156x over previous
//
#include <hip/hip_runtime.h>
#include <hip/hip_bf16.h>

#define HWSZ 12544   // 112*112
#define WDIM 112
#define CIN  128
#define NPIX 25088   // B*HWSZ, B=2
#define VTROW 6272   // 112*56 = one (b,parity,ch) plane of vt (hw>>1 indexed)

typedef __attribute__((ext_vector_type(8))) short          short8;
typedef __attribute__((ext_vector_type(4))) float          float4v;
typedef __attribute__((ext_vector_type(4))) unsigned short ushort4v;

// NATTEN window start for K=7, D=2
__device__ __forceinline__ int window_start7x2(int idx, int L) {
    int ni = idx - 6;
    int imodd = idx & 1;
    int a = (L >> 1) << 1;
    int bb = L - a;
    int right = (imodd < bb) ? (L - bb + imodd - 12) : (a + imodd - 14);
    if (ni < 0) return imodd;
    if (idx + 6 >= L) return right;
    return ni;
}

__device__ __forceinline__ unsigned short f2bf(float f) {
    __hip_bfloat16 h = __float2bfloat16(f);
    return *(unsigned short*)&h;
}

// ---------------------------------------------------------------------------
// Projection GEMM via MFMA. A-fragments direct from x; W staged in LDS.
// grid (392, 3) x 256 thr. m==0: q, m==1: k (natural [pix][64]); m==2: v as
// parity-split transposed vt[(b*2+parity)*64+ch][hw>>1]. All epilogues go
// through an LDS transpose so global stores are 2xb128/thread, coalesced.
// ---------------------------------------------------------------------------
__global__ __launch_bounds__(256) void proj_mfma(
    const float* __restrict__ x,
    const float* __restrict__ Wq, const float* __restrict__ bq,
    const float* __restrict__ Wk, const float* __restrict__ bk,
    const float* __restrict__ Wv, const float* __restrict__ bv,
    unsigned short* __restrict__ qbuf)
{
    __shared__ __align__(16) unsigned short wsb[64][136];  // [out][c], pad 8
    __shared__ __align__(16) unsigned short trans[64 * 80]; // epilogue transpose

    const int t = threadIdx.x, lane = t & 63, wv = t >> 6, quad = lane >> 4;
    const int col = lane & 15;
    const int m = blockIdx.y;
    const float* Wm = (m == 0) ? Wq : (m == 1) ? Wk : Wv;
    const float* bm = (m == 0) ? bq : (m == 1) ? bk : bv;

    const int pix0 = blockIdx.x * 64;           // HWSZ % 64 == 0: no b-straddle
    const int b    = blockIdx.x / 196;
    const int hw0  = pix0 - b * HWSZ;
    const float* xb = x + (size_t)b * CIN * HWSZ;

    // stage W tile [out][c] (fp32 -> bf16)
    #pragma unroll
    for (int i = 0; i < 8; ++i) {
        int u = t + 256 * i;
        int o = u >> 5, cq = (u & 31) * 4;
        float4 w4 = *(const float4*)&Wm[o * 128 + cq];
        ushort4v s4 = { f2bf(w4.x), f2bf(w4.y), f2bf(w4.z), f2bf(w4.w) };
        *(ushort4v*)&wsb[o][cq] = s4;
    }

    // A-fragments direct from global: px = wv*16+col, ch = kc*32+quad*8+j
    const int hwpx = hw0 + wv * 16 + col;
    short8 af[4];
    #pragma unroll
    for (int kc = 0; kc < 4; ++kc) {
        #pragma unroll
        for (int j = 0; j < 8; ++j) {
            int c = kc * 32 + quad * 8 + j;
            af[kc][j] = (short)f2bf(xb[(size_t)c * HWSZ + hwpx]);
        }
    }
    __syncthreads();

    float4v acc[4] = {{0,0,0,0},{0,0,0,0},{0,0,0,0},{0,0,0,0}};
    #pragma unroll
    for (int kc = 0; kc < 4; ++kc) {
        #pragma unroll
        for (int nt = 0; nt < 4; ++nt) {
            short8 bf = *(const short8*)&wsb[nt * 16 + col][kc * 32 + quad * 8];
            acc[nt] = __builtin_amdgcn_mfma_f32_16x16x32_bf16(af[kc], bf, acc[nt], 0, 0, 0);
        }
    }
    __syncthreads();   // wsb dead; trans about to be written

    if (m < 2) {
        // stage [px][o], pitch 80
        #pragma unroll
        for (int nt = 0; nt < 4; ++nt) {
            float bias = bm[nt * 16 + col];
            #pragma unroll
            for (int r = 0; r < 4; ++r) {
                int px = wv * 16 + quad * 4 + r;    // D: row = quad*4 + reg
                trans[px * 80 + nt * 16 + col] = f2bf(acc[nt][r] + bias);
            }
        }
        __syncthreads();
        unsigned short* outm = qbuf + (size_t)m * NPIX * 64;
        const int tpx = t >> 2, chunk = t & 3;
        const unsigned short* src = &trans[tpx * 80 + chunk * 16];
        unsigned short* dst = outm + (size_t)(pix0 + tpx) * 64 + chunk * 16;
        *(short8*)(dst)     = *(const short8*)(src);
        *(short8*)(dst + 8) = *(const short8*)(src + 8);
    } else {
        // stage [ch][parity*40 + px>>1], pitch 80
        #pragma unroll
        for (int nt = 0; nt < 4; ++nt) {
            int ch = nt * 16 + col;
            float bias = bm[ch];
            #pragma unroll
            for (int r = 0; r < 4; ++r) {
                int px = wv * 16 + quad * 4 + r;
                trans[ch * 80 + (px & 1) * 40 + (px >> 1)] = f2bf(acc[nt][r] + bias);
            }
        }
        __syncthreads();
        unsigned short* vt = qbuf + 2 * (size_t)NPIX * 64;
        const int ch = t >> 2, parity = (t >> 1) & 1, half = t & 1;
        const unsigned short* src = &trans[ch * 80 + parity * 40 + half * 16];
        // hw>>1 is continuous across h rows: no straddle, ever
        unsigned short* dst = vt + (size_t)((b * 2 + parity) * 64 + ch) * VTROW
                            + (hw0 >> 1) + half * 16;
        *(short8*)(dst)     = *(const short8*)(src);
        *(short8*)(dst + 8) = *(const short8*)(src + 8);
    }
}

// ---------------------------------------------------------------------------
// Attention: ONE WAVE per 16-px tile, 64-thread blocks, no barriers.
// Key space u = i*32 + c (7 rows x 32 padded cols rel. to 8-aligned cb0).
// S in registers; softmax in-register; P -> LDS for D->A transform; PV B-frags
// are single b128 loads from vt. V addresses precomputed and first-kc frags
// prefetched before softmax. grid 1792 x 64 thr.
// ---------------------------------------------------------------------------
__global__ __launch_bounds__(64) void attn_mfma(
    const unsigned short* __restrict__ qkv, float* __restrict__ out)
{
    __shared__ __align__(16) unsigned short ps[16 * 232];   // [px][u], pitch 232

    const int lane = threadIdx.x, quad = lane >> 4, col = lane & 15;
    const int bx  = blockIdx.x;
    const int b   = bx / 896;  const int rem = bx - b * 896;
    const int h   = rem >> 3;  const int sub = rem & 7;
    const int g   = sub & 1;
    const int pbi = sub >> 1;
    const int pb  = (pbi < 3) ? pbi * 16 : 40;   // last tile overlaps (benign)

    const int hs  = window_start7x2(h, WDIM);
    const int ws0 = window_start7x2(2 * pb + g, WDIM);
    const int cb0 = (ws0 >> 1) & ~7;             // 8-aligned col base
    const int pixbase = b * HWSZ;

    const unsigned short* qg = qkv;
    const unsigned short* kg = qkv + (size_t)NPIX * 64;
    const unsigned short* vt = qkv + 2 * (size_t)NPIX * 64
                             + (size_t)(b * 2 + g) * 64 * VTROW;

    // ---- Q A-fragments (m = col = px, k = ch)
    const int qpix = pixbase + h * WDIM + 2 * (pb + col) + g;
    short8 af0 = *(const short8*)(qg + (size_t)qpix * 64 + quad * 8);
    short8 af1 = *(const short8*)(qg + (size_t)qpix * 64 + 32 + quad * 8);

    // per-lane window col bases (relative to cb0) for rows px = quad*4 + r
    int cbr[4];
    #pragma unroll
    for (int r = 0; r < 4; ++r)
        cbr[r] = (window_start7x2(2 * (pb + quad * 4 + r) + g, WDIM) >> 1) - cb0;

    // PV V-row offsets (independent of scores) + first-kc prefetch
    int rowoff[7];
    #pragma unroll
    for (int kc = 0; kc < 7; ++kc) {
        int u8 = kc * 32 + quad * 8;
        rowoff[kc] = (hs + 2 * (u8 >> 5)) * 56 + cb0 + (u8 & 31);  // 16B aligned
    }
    short8 vb0[4];
    #pragma unroll
    for (int nt = 0; nt < 4; ++nt)
        vb0[nt] = *(const short8*)(vt + (size_t)(nt * 16 + col) * VTROW + rowoff[0]);

    // ---- scores: S[16][224], 14 n-tiles x 2 MFMA (K-dim = 64 ch)
    float4v S[14];
    #pragma unroll
    for (int nt = 0; nt < 14; ++nt) {
        int u = nt * 16 + col;
        int i = u >> 5, c = u & 31;
        int wcol = cb0 + c;
        int kw = 2 * wcol + g; kw = (kw > 111) ? 111 : kw;   // addr guard
        int kp = pixbase + (hs + 2 * i) * WDIM + kw;
        float4v a = {0, 0, 0, 0};
        a = __builtin_amdgcn_mfma_f32_16x16x32_bf16(
                af0, *(const short8*)(kg + (size_t)kp * 64 + quad * 8), a, 0, 0, 0);
        a = __builtin_amdgcn_mfma_f32_16x16x32_bf16(
                af1, *(const short8*)(kg + (size_t)kp * 64 + 32 + quad * 8), a, 0, 0, 0);
        bool colok = (wcol <= 55);
        #pragma unroll
        for (int r = 0; r < 4; ++r) {
            bool valid = colok && ((unsigned)(c - cbr[r]) < 7u);
            S[nt][r] = valid ? a[r] * 0.125f : -1e30f;   // scale = 64^-0.5
        }
    }

    // ---- softmax per row (row = quad*4 + r; cols spread over 16 lanes x 14 nt)
    #pragma unroll
    for (int r = 0; r < 4; ++r) {
        float mx = S[0][r];
        #pragma unroll
        for (int nt = 1; nt < 14; ++nt) mx = fmaxf(mx, S[nt][r]);
        #pragma unroll
        for (int msk = 1; msk < 16; msk <<= 1)
            mx = fmaxf(mx, __shfl_xor(mx, msk, 64));
        float sum = 0.0f;
        #pragma unroll
        for (int nt = 0; nt < 14; ++nt) {
            float e = __expf(S[nt][r] - mx);    // masked -> 0
            S[nt][r] = e;
            sum += e;
        }
        #pragma unroll
        for (int msk = 1; msk < 16; msk <<= 1)
            sum += __shfl_xor(sum, msk, 64);
        float rinv = 1.0f / sum;
        int row = quad * 4 + r;
        #pragma unroll
        for (int nt = 0; nt < 14; ++nt)
            ps[row * 232 + nt * 16 + col] = f2bf(S[nt][r] * rinv);
    }
    // no barrier needed: single wave, lgkmcnt orders ds_write -> ds_read

    // ---- PV: O[16][64] = P(16x224) * V(224x64)
    float4v O[4] = {{0,0,0,0},{0,0,0,0},{0,0,0,0},{0,0,0,0}};
    {
        short8 pa = *(const short8*)&ps[col * 232 + quad * 8];
        #pragma unroll
        for (int nt = 0; nt < 4; ++nt)
            O[nt] = __builtin_amdgcn_mfma_f32_16x16x32_bf16(pa, vb0[nt], O[nt], 0, 0, 0);
    }
    #pragma unroll
    for (int kc = 1; kc < 7; ++kc) {
        short8 pa = *(const short8*)&ps[col * 232 + kc * 32 + quad * 8];
        #pragma unroll
        for (int nt = 0; nt < 4; ++nt) {
            short8 vb = *(const short8*)(vt + (size_t)(nt * 16 + col) * VTROW + rowoff[kc]);
            O[nt] = __builtin_amdgcn_mfma_f32_16x16x32_bf16(pa, vb, O[nt], 0, 0, 0);
        }
    }

    // ---- store (B, C, H, W); D: row px = quad*4+r, col ch = nt*16+col
    #pragma unroll
    for (int nt = 0; nt < 4; ++nt) {
        int ch = nt * 16 + col;
        float* ob = out + (size_t)(b * 64 + ch) * HWSZ + h * WDIM;
        #pragma unroll
        for (int r = 0; r < 4; ++r)
            ob[2 * (pb + quad * 4 + r) + g] = O[nt][r];
    }
}

// ---------------------------------------------------------------------------
extern "C" void kernel_launch(void* const* d_in, const int* in_sizes, int n_in,
                              void* d_out, int out_size, void* d_ws, size_t ws_size,
                              hipStream_t stream) {
    const float* x  = (const float*)d_in[0];
    const float* Wq = (const float*)d_in[1];
    const float* bq = (const float*)d_in[2];
    const float* Wk = (const float*)d_in[3];
    const float* bk = (const float*)d_in[4];
    const float* Wv = (const float*)d_in[5];
    const float* bv = (const float*)d_in[6];
    float* out = (float*)d_out;

    // d_ws: q [NPIX][64] u16 | k [NPIX][64] u16 | vt [256][VTROW] u16 (+slack)
    unsigned short* qkv = (unsigned short*)d_ws;

    proj_mfma<<<dim3(392, 3), dim3(256), 0, stream>>>(x, Wq, bq, Wk, bk, Wv, bv, qkv);
    attn_mfma<<<dim3(1792), dim3(64), 0, stream>>>(qkv, out);
}